// Round 1
// baseline (2185.448 us; speedup 1.0000x reference)
//
#include <hip/hip_runtime.h>

#define D 64

// y[row][j] (+)= sum_i xin[row][i] * W[j][i] + b[j]
__global__ __launch_bounds__(256) void tap_kernel(
    const float* __restrict__ xin, const float* __restrict__ W,
    const float* __restrict__ b, float* __restrict__ y,
    int n_nodes, int first)
{
    __shared__ float Wt[D * (D + 1)];   // Wt[i*(D+1)+j] = W[j][i]  (padded: conflict-free)
    __shared__ float bs[D];
    __shared__ float xs[4][D];

    int tid = threadIdx.x;
    // load W transposed into LDS
    for (int t = tid; t < D * D; t += 256) {
        int j = t >> 6, i = t & 63;
        Wt[i * (D + 1) + j] = W[t];
    }
    if (tid < D) bs[tid] = b[tid];

    int rl = tid >> 6;          // row within block (0..3)
    int j  = tid & 63;          // output column
    int row = blockIdx.x * 4 + rl;
    if (row < n_nodes) xs[rl][j] = xin[row * D + j];
    __syncthreads();

    if (row >= n_nodes) return;

    float acc = bs[j];
    #pragma unroll 8
    for (int i = 0; i < D; ++i)
        acc = fmaf(xs[rl][i], Wt[i * (D + 1) + j], acc);

    float* yp = y + row * D + j;
    *yp = first ? acc : (*yp + acc);
}

// xout[dst[e]][:] += xin[src[e]][:]   (16 lanes per edge, float4 gather, 4 atomics/lane)
__global__ __launch_bounds__(256) void scatter_kernel(
    const float* __restrict__ xin, float* __restrict__ xout,
    const int* __restrict__ src, const int* __restrict__ dst, int n_edges)
{
    int t = blockIdx.x * blockDim.x + threadIdx.x;
    int e = t >> 4;
    if (e >= n_edges) return;
    int c = (t & 15) * 4;

    int s = src[e];
    int d = dst[e];
    const float4 v = *reinterpret_cast<const float4*>(xin + (size_t)s * D + c);
    float* o = xout + (size_t)d * D + c;
    atomicAdd(o + 0, v.x);
    atomicAdd(o + 1, v.y);
    atomicAdd(o + 2, v.z);
    atomicAdd(o + 3, v.w);
}

extern "C" void kernel_launch(void* const* d_in, const int* in_sizes, int n_in,
                              void* d_out, int out_size, void* d_ws, size_t ws_size,
                              hipStream_t stream) {
    const float* x  = (const float*)d_in[0];
    const int*   ei = (const int*)d_in[1];
    const float* W  = (const float*)d_in[2];
    const float* b  = (const float*)d_in[3];
    float* y = (float*)d_out;

    int n_nodes = in_sizes[0] / D;   // 50000
    int n_edges = in_sizes[1] / 2;   // 800000
    const int* src = ei;
    const int* dst = ei + n_edges;

    size_t bufBytes = (size_t)n_nodes * D * sizeof(float);
    float* A = (float*)d_ws;
    float* B = (float*)((char*)d_ws + bufBytes);

    dim3 tb(256);
    dim3 tg((n_nodes + 3) / 4);
    int sgrid = (n_edges * 16 + 255) / 256;

    hipMemsetAsync(A, 0, bufBytes, stream);
    hipMemsetAsync(B, 0, bufBytes, stream);

    // tap 0: y = x @ W0^T + b0
    tap_kernel<<<tg, tb, 0, stream>>>(x, W, b, y, n_nodes, 1);

    // shift 1: A = S x ; y += A @ W1^T + b1
    scatter_kernel<<<sgrid, tb, 0, stream>>>(x, A, src, dst, n_edges);
    tap_kernel<<<tg, tb, 0, stream>>>(A, W + D * D, b + D, y, n_nodes, 0);

    // shift 2: B = S A ; y += B @ W2^T + b2
    scatter_kernel<<<sgrid, tb, 0, stream>>>(A, B, src, dst, n_edges);
    hipMemsetAsync(A, 0, bufBytes, stream);   // A free; re-zero for shift 3
    tap_kernel<<<tg, tb, 0, stream>>>(B, W + 2 * D * D, b + 2 * D, y, n_nodes, 0);

    // shift 3: A = S B ; y += A @ W3^T + b3
    scatter_kernel<<<sgrid, tb, 0, stream>>>(B, A, src, dst, n_edges);
    tap_kernel<<<tg, tb, 0, stream>>>(A, W + 3 * D * D, b + 3 * D, y, n_nodes, 0);
}

// Round 2
// 300.456 us; speedup vs baseline: 7.2738x; 7.2738x over previous
//
#include <hip/hip_runtime.h>

#define D 64
#define SCAN_CHUNK 1024   // elements per scan1 block (256 thr x 4)

// ---------------- taps: y[row][j] (+)= sum_i xin[row][i]*W[j][i] + b[j] ----
__global__ __launch_bounds__(256) void tap_kernel(
    const float* __restrict__ xin, const float* __restrict__ W,
    const float* __restrict__ b, float* __restrict__ y,
    int n_nodes, int first)
{
    __shared__ float Wt[D * (D + 1)];
    __shared__ float bs[D];
    __shared__ float xs[4][D];

    int tid = threadIdx.x;
    for (int t = tid; t < D * D; t += 256) {
        int j = t >> 6, i = t & 63;
        Wt[i * (D + 1) + j] = W[t];
    }
    if (tid < D) bs[tid] = b[tid];

    int rl = tid >> 6;
    int j  = tid & 63;
    int row = blockIdx.x * 4 + rl;
    if (row < n_nodes) xs[rl][j] = xin[row * D + j];
    __syncthreads();

    if (row >= n_nodes) return;

    float acc = bs[j];
    #pragma unroll 8
    for (int i = 0; i < D; ++i)
        acc = fmaf(xs[rl][i], Wt[i * (D + 1) + j], acc);

    float* yp = y + row * D + j;
    *yp = first ? acc : (*yp + acc);
}

// ---------------- CSR build ------------------------------------------------
__global__ __launch_bounds__(256) void hist_kernel(
    const int* __restrict__ dst, int* __restrict__ counts, int n_edges)
{
    int e = blockIdx.x * 256 + threadIdx.x;
    if (e < n_edges) atomicAdd(&counts[dst[e]], 1);
}

// per-block (1024-elem chunk) exclusive scan; block totals to bsum
__global__ __launch_bounds__(256) void scan1_kernel(
    const int* __restrict__ counts, int* __restrict__ excl,
    int* __restrict__ bsum, int n)
{
    __shared__ int lds[256];
    int tid = threadIdx.x;
    int base = blockIdx.x * SCAN_CHUNK + tid * 4;
    int c0 = 0, c1 = 0, c2 = 0, c3 = 0;
    if (base + 3 < n) {
        int4 v = *reinterpret_cast<const int4*>(counts + base);
        c0 = v.x; c1 = v.y; c2 = v.z; c3 = v.w;
    } else {
        if (base + 0 < n) c0 = counts[base + 0];
        if (base + 1 < n) c1 = counts[base + 1];
        if (base + 2 < n) c2 = counts[base + 2];
        if (base + 3 < n) c3 = counts[base + 3];
    }
    int s = c0 + c1 + c2 + c3;
    lds[tid] = s;
    __syncthreads();
    for (int off = 1; off < 256; off <<= 1) {
        int v = (tid >= off) ? lds[tid - off] : 0;
        __syncthreads();
        lds[tid] += v;
        __syncthreads();
    }
    int incl = lds[tid];
    int ex = incl - s;
    if (tid == 255) bsum[blockIdx.x] = incl;
    if (base + 0 < n) excl[base + 0] = ex;
    if (base + 1 < n) excl[base + 1] = ex + c0;
    if (base + 2 < n) excl[base + 2] = ex + c0 + c1;
    if (base + 3 < n) excl[base + 3] = ex + c0 + c1 + c2;
}

// exclusive scan of block sums (nb <= 64), single wave
__global__ __launch_bounds__(64) void scan2_kernel(int* __restrict__ bsum, int nb)
{
    int lane = threadIdx.x;
    int v = (lane < nb) ? bsum[lane] : 0;
    int orig = v;
    for (int off = 1; off < 64; off <<= 1) {
        int t = __shfl_up(v, off);
        if (lane >= off) v += t;
    }
    if (lane < nb) bsum[lane] = v - orig;
}

__global__ __launch_bounds__(256) void scan3_kernel(
    const int* __restrict__ excl, const int* __restrict__ bsum,
    int* __restrict__ rp, int n, int n_edges)
{
    int i = blockIdx.x * 256 + threadIdx.x;
    if (i < n) rp[i] = excl[i] + bsum[i / SCAN_CHUNK];
    if (i == 0) rp[n] = n_edges;
}

__global__ __launch_bounds__(256) void fill_kernel(
    const int* __restrict__ src, const int* __restrict__ dst,
    const int* __restrict__ rp, int* __restrict__ cursor,
    int* __restrict__ csr, int n_edges)
{
    int e = blockIdx.x * 256 + threadIdx.x;
    if (e >= n_edges) return;
    int d = dst[e];
    int p = rp[d] + atomicAdd(&cursor[d], 1);
    csr[p] = src[e];
}

// ---------------- pull aggregation: xout[v] = sum_{e: dst=v} xin[src[e]] ---
__global__ __launch_bounds__(256) void pull_kernel(
    const float* __restrict__ xin, float* __restrict__ xout,
    const int* __restrict__ rp, const int* __restrict__ csr, int n_nodes)
{
    int wid  = (blockIdx.x * 256 + threadIdx.x) >> 6;   // node
    int lane = threadIdx.x & 63;                        // column
    if (wid >= n_nodes) return;
    int beg = rp[wid], end = rp[wid + 1];
    float acc = 0.f;
    for (int e = beg; e < end; e += 64) {
        int cnt = end - e;
        if (cnt > 64) cnt = 64;
        int idx = (lane < cnt) ? csr[e + lane] : 0;     // coalesced index block
        int i = 0;
        for (; i + 4 <= cnt; i += 4) {
            int s0 = __shfl(idx, i);
            int s1 = __shfl(idx, i + 1);
            int s2 = __shfl(idx, i + 2);
            int s3 = __shfl(idx, i + 3);
            float a0 = xin[(size_t)s0 * D + lane];
            float a1 = xin[(size_t)s1 * D + lane];
            float a2 = xin[(size_t)s2 * D + lane];
            float a3 = xin[(size_t)s3 * D + lane];
            acc += (a0 + a1) + (a2 + a3);
        }
        for (; i < cnt; ++i) {
            int s = __shfl(idx, i);
            acc += xin[(size_t)s * D + lane];
        }
    }
    xout[(size_t)wid * D + lane] = acc;
}

// ---------------- fallback (atomic push) if ws too small -------------------
__global__ __launch_bounds__(256) void scatter_kernel(
    const float* __restrict__ xin, float* __restrict__ xout,
    const int* __restrict__ src, const int* __restrict__ dst, int n_edges)
{
    int t = blockIdx.x * blockDim.x + threadIdx.x;
    int e = t >> 4;
    if (e >= n_edges) return;
    int c = (t & 15) * 4;
    int s = src[e];
    int d = dst[e];
    const float4 v = *reinterpret_cast<const float4*>(xin + (size_t)s * D + c);
    float* o = xout + (size_t)d * D + c;
    atomicAdd(o + 0, v.x);
    atomicAdd(o + 1, v.y);
    atomicAdd(o + 2, v.z);
    atomicAdd(o + 3, v.w);
}

extern "C" void kernel_launch(void* const* d_in, const int* in_sizes, int n_in,
                              void* d_out, int out_size, void* d_ws, size_t ws_size,
                              hipStream_t stream) {
    const float* x  = (const float*)d_in[0];
    const int*   ei = (const int*)d_in[1];
    const float* W  = (const float*)d_in[2];
    const float* b  = (const float*)d_in[3];
    float* y = (float*)d_out;

    int n_nodes = in_sizes[0] / D;   // 50000
    int n_edges = in_sizes[1] / 2;   // 800000
    const int* src = ei;
    const int* dst = ei + n_edges;

    int n_pad = ((n_nodes + SCAN_CHUNK - 1) / SCAN_CHUNK) * SCAN_CHUNK; // 50176
    int nblk  = n_pad / SCAN_CHUNK;                                      // 49

    size_t bufElems = (size_t)n_nodes * D;
    float* A = (float*)d_ws;
    float* B = A + bufElems;
    int* counts = (int*)(B + bufElems);
    int* excl   = counts + n_pad;
    int* rp     = excl + n_pad;        // n_nodes+1 used
    int* cursor = rp + n_pad;
    int* bsum   = cursor + n_pad;      // 64
    int* csr    = bsum + 64;           // n_edges

    size_t needed = (char*)(csr + n_edges) - (char*)d_ws;

    dim3 tb(256);
    dim3 tg((n_nodes + 3) / 4);
    int egrid = (n_edges + 255) / 256;
    int ngrid = (n_nodes + 255) / 256;
    int pgrid = (n_nodes * 64 + 255) / 256;

    if (needed <= ws_size) {
        // ---- CSR build ----
        hipMemsetAsync(counts, 0, (size_t)n_pad * sizeof(int), stream);
        hipMemsetAsync(cursor, 0, (size_t)n_pad * sizeof(int), stream);
        hist_kernel<<<egrid, tb, 0, stream>>>(dst, counts, n_edges);
        scan1_kernel<<<nblk, tb, 0, stream>>>(counts, excl, bsum, n_nodes);
        scan2_kernel<<<1, 64, 0, stream>>>(bsum, nblk);
        scan3_kernel<<<ngrid, tb, 0, stream>>>(excl, bsum, rp, n_nodes, n_edges);
        fill_kernel<<<egrid, tb, 0, stream>>>(src, dst, rp, cursor, csr, n_edges);

        // ---- taps + pull shifts ----
        tap_kernel<<<tg, tb, 0, stream>>>(x, W, b, y, n_nodes, 1);

        pull_kernel<<<pgrid, tb, 0, stream>>>(x, A, rp, csr, n_nodes);
        tap_kernel<<<tg, tb, 0, stream>>>(A, W + D * D, b + D, y, n_nodes, 0);

        pull_kernel<<<pgrid, tb, 0, stream>>>(A, B, rp, csr, n_nodes);
        tap_kernel<<<tg, tb, 0, stream>>>(B, W + 2 * D * D, b + 2 * D, y, n_nodes, 0);

        pull_kernel<<<pgrid, tb, 0, stream>>>(B, A, rp, csr, n_nodes);
        tap_kernel<<<tg, tb, 0, stream>>>(A, W + 3 * D * D, b + 3 * D, y, n_nodes, 0);
    } else {
        // ---- fallback: atomic push path ----
        size_t bufBytes = bufElems * sizeof(float);
        int sgrid = (n_edges * 16 + 255) / 256;
        hipMemsetAsync(A, 0, bufBytes, stream);
        hipMemsetAsync(B, 0, bufBytes, stream);
        tap_kernel<<<tg, tb, 0, stream>>>(x, W, b, y, n_nodes, 1);
        scatter_kernel<<<sgrid, tb, 0, stream>>>(x, A, src, dst, n_edges);
        tap_kernel<<<tg, tb, 0, stream>>>(A, W + D * D, b + D, y, n_nodes, 0);
        scatter_kernel<<<sgrid, tb, 0, stream>>>(A, B, src, dst, n_edges);
        hipMemsetAsync(A, 0, bufBytes, stream);
        tap_kernel<<<tg, tb, 0, stream>>>(B, W + 2 * D * D, b + 2 * D, y, n_nodes, 0);
        scatter_kernel<<<sgrid, tb, 0, stream>>>(B, A, src, dst, n_edges);
        tap_kernel<<<tg, tb, 0, stream>>>(A, W + 3 * D * D, b + 3 * D, y, n_nodes, 0);
    }
}